// Round 6
// baseline (884.850 us; speedup 1.0000x reference)
//
#include <hip/hip_runtime.h>
#include <cstdint>
#include <cstddef>

// Problem constants
#define Bb   256
#define Tt   512
#define Ii   300
#define Hh   128
#define G4   512      // 4*H
#define KP   320      // K padded to multiple of 32 for MFMA
#define Mm   (Bb*Tt)  // 131072 rows of phase-1 GEMM

typedef _Float16 h2v   __attribute__((ext_vector_type(2)));
typedef _Float16 half8 __attribute__((ext_vector_type(8)));
typedef float    f32x4 __attribute__((ext_vector_type(4)));

static __device__ __forceinline__ h2v as_h2(unsigned int u){ union{unsigned int u; h2v h;} c; c.u=u; return c.h; }
static __device__ __forceinline__ unsigned int as_u32(h2v h){ union{unsigned int u; h2v h;} c; c.h=h; return c.u; }

#if __has_builtin(__builtin_amdgcn_fdot2)
#define FDOT2(a,b,c) __builtin_amdgcn_fdot2((a),(b),(c),false)
#else
static __device__ __forceinline__ float FDOT2(h2v a, h2v b, float c){
  return c + (float)a[0]*(float)b[0] + (float)a[1]*(float)b[1];
}
#endif

// quad_perm DPP: permute within each 4-lane group, 1 VALU instr.
template<int CTRL>
static __device__ __forceinline__ float qperm(float v){
  union{float f; int i;} c; c.f = v;
  c.i = __builtin_amdgcn_update_dpp(c.i, c.i, CTRL, 0xF, 0xF, false);
  return c.f;
}
#define QP_XOR1 0xB1   // quad_perm [1,0,3,2]  : lane^1
#define QP_XOR2 0x4E   // quad_perm [2,3,0,1]  : lane^2
#define QP_XOR3 0x1B   // quad_perm [3,2,1,0]  : lane^3

// ---------------- conversion: W_ih -> f16 padded (rows PERMUTED pr=d*4+g), Whh packed, bias sum ---
// Row permutation: output row pr corresponds to original gate row gc = (pr&3)*128 + (pr>>2).
// Whh packed for lstm_rec: thread pr (=d*4+g) holds half2 kk=0..63 -> Whh2[pr*64 + kk].
__global__ __launch_bounds__(256) void conv_small(const float* __restrict__ Wih, const float* __restrict__ Whh,
      const float* __restrict__ bih, const float* __restrict__ bhh,
      unsigned int* __restrict__ W16, unsigned int* __restrict__ Whh2, float* __restrict__ bias){
  int idx = blockIdx.x*256 + threadIdx.x;
  if (idx < G4*160){
    int pr = idx/160, kk2 = idx - pr*160, kk = kk2*2;
    int gc = (pr&3)*128 + (pr>>2);
    const float* wr = Wih + (size_t)gc*Ii;
    float v0 = (kk   < Ii) ? wr[kk]   : 0.f;
    float v1 = (kk+1 < Ii) ? wr[kk+1] : 0.f;
    h2v h; h[0]=(_Float16)v0; h[1]=(_Float16)v1;
    W16[idx] = as_u32(h);
  } else if (idx < G4*160 + G4*64){
    int t = idx - G4*160; int pr = t>>6, kk = t&63;
    int gc = (pr&3)*128 + (pr>>2);
    float v0 = Whh[gc*Hh + kk*2], v1 = Whh[gc*Hh + kk*2 + 1];
    h2v h; h[0]=(_Float16)v0; h[1]=(_Float16)v1;
    Whh2[t] = as_u32(h);
  } else if (idx < G4*160 + G4*64 + G4){
    int pr = idx - (G4*160 + G4*64);
    int gc = (pr&3)*128 + (pr>>2);
    bias[pr] = bih[gc] + bhh[gc];
  }
}

// ---------------- phase 1: xg[131072,512] = cvt16(x) @ W16^T + bias, f16 MFMA ----------------
// A-side reads x directly as f32 and converts in-register (conv_x kernel eliminated).
// Register-prefetch pipeline: tile kt+1 global loads issue right after the LDS write
// of tile kt, so their latency drains behind the MFMA block + barrier.
// Note Ii=300 is a multiple of 4, so every float4 is fully in-row (c<=296) or fully pad (c>=300).
__global__ __launch_bounds__(256,2) void gemm16(const float* __restrict__ X, const _Float16* __restrict__ Bm,
       const float* __restrict__ bias, float* __restrict__ C){
  __shared__ _Float16 As[128][32];
  __shared__ _Float16 Bs[128][32];
  int tid = threadIdx.x;
  int w = tid>>6, lane = tid&63;
  int bm = blockIdx.x*128, bn = blockIdx.y*128;
  f32x4 acc[2][8];
  #pragma unroll
  for (int i=0;i<2;i++)
    #pragma unroll
    for (int j=0;j<8;j++) acc[i][j] = (f32x4){0.f,0.f,0.f,0.f};

  int srow = tid>>1, scol = (tid&1)*16;   // this thread stages 16 cols of row srow
  const float*    xr = X  + (size_t)(bm+srow)*Ii;   // f32 row, 300 valid cols
  const _Float16* br = Bm + (size_t)(bn+srow)*KP;   // f16 row, padded to 320

  int q = lane>>4, mr = lane&15;
  int m0 = w*32;

  float4 a4[4];
  uint4  b4[2];
  // prefetch kt=0
  {
    #pragma unroll
    for (int i=0;i<4;i++){
      int c = scol + i*4;
      a4[i] = (c <= Ii-4) ? *(const float4*)(xr + c) : (float4){0.f,0.f,0.f,0.f};
    }
    b4[0] = *(const uint4*)(br + scol);
    b4[1] = *(const uint4*)(br + scol + 8);
  }

  for (int kt=0; kt<KP/32; ++kt){
    __syncthreads();
    // convert prefetched A to f16, store A+B tiles
    union { _Float16 h[16]; uint4 u[2]; } ah;
    #pragma unroll
    for (int i=0;i<4;i++){
      ah.h[i*4+0] = (_Float16)a4[i].x;
      ah.h[i*4+1] = (_Float16)a4[i].y;
      ah.h[i*4+2] = (_Float16)a4[i].z;
      ah.h[i*4+3] = (_Float16)a4[i].w;
    }
    *(uint4*)&As[srow][scol]   = ah.u[0];
    *(uint4*)&As[srow][scol+8] = ah.u[1];
    *(uint4*)&Bs[srow][scol]   = b4[0];
    *(uint4*)&Bs[srow][scol+8] = b4[1];
    // issue next-tile loads (consumed after the next barrier -> latency hidden)
    if (kt+1 < KP/32){
      int c0 = (kt+1)*32 + scol;
      #pragma unroll
      for (int i=0;i<4;i++){
        int c = c0 + i*4;
        a4[i] = (c <= Ii-4) ? *(const float4*)(xr + c) : (float4){0.f,0.f,0.f,0.f};
      }
      const _Float16* bb = br + (kt+1)*32;
      b4[0] = *(const uint4*)(bb + scol);
      b4[1] = *(const uint4*)(bb + scol + 8);
    }
    __syncthreads();
    half8 af0 = *(const half8*)&As[m0 + mr][q*8];
    half8 af1 = *(const half8*)&As[m0 + 16 + mr][q*8];
    #pragma unroll
    for (int j=0;j<8;j++){
      half8 bf = *(const half8*)&Bs[j*16 + mr][q*8];
      acc[0][j] = __builtin_amdgcn_mfma_f32_16x16x32_f16(af0, bf, acc[0][j], 0,0,0);
      acc[1][j] = __builtin_amdgcn_mfma_f32_16x16x32_f16(af1, bf, acc[1][j], 0,0,0);
    }
  }
  // epilogue: C/D layout col=lane&15, row=(lane>>4)*4+reg
  #pragma unroll
  for (int j=0;j<8;j++){
    int gc = bn + j*16 + mr;
    float bv = bias[gc];
    #pragma unroll
    for (int i=0;i<2;i++){
      int gr0 = bm + w*32 + i*16 + q*4;
      #pragma unroll
      for (int reg=0; reg<4; ++reg)
        C[(size_t)(gr0+reg)*G4 + gc] = acc[i][j][reg] + bv;
    }
  }
}

// ---------------- phase 2: recurrence, one block per batch row (R1 structure) ----------------
// 512 threads, tid = d*4 + g. The 4 gate replicas of a dim are ADJACENT LANES of one
// wave: gate exchange = quad_perm DPP (pure VALU, no LDS, no barrier). Only the h
// broadcast crosses waves; double-buffered hsh makes ONE __syncthreads per step
// sufficient. xg prefetched 2 steps deep to cover ~900-cyc HBM miss latency.
__global__ __launch_bounds__(512,1) void lstm_rec(const float* __restrict__ xg, const unsigned int* __restrict__ Whh2,
     const float* __restrict__ fcw, const float* __restrict__ fcb, float* __restrict__ out){
  int tid = threadIdx.x;           // 0..511
  int b = blockIdx.x;
  int d = tid >> 2, g = tid & 3;
  h2v w[64];
  #pragma unroll
  for (int kk=0; kk<64; ++kk) w[kk] = as_h2(Whh2[tid*64 + kk]);

  __shared__ __align__(16) unsigned short hsh[2][128];
  __shared__ float red[128];
  if (tid < 128) hsh[0][tid] = 0;
  float creg = 0.f, hreg = 0.f;
  const float* xrow = xg + (size_t)b * (Tt*G4);
  float xc = xrow[tid];
  float xa = xrow[G4 + tid];
  int b0 = g & 1;
  int b1 = (g >> 1) & 1;
  float km = (g == 2) ? 2.f : 1.f;   // tanh(a) = 2*sigmoid(2a)-1
  __syncthreads();

  for (int t=0; t<Tt; ++t){
    // next-next-step load first (tail clamped; clamped value never consumed)
    int tl = (t+2 < Tt) ? (t+2) : (Tt-1);
    float xb = xrow[(size_t)tl*G4 + tid];

    const uint4* hv = (const uint4*)hsh[t & 1];
    float a0 = xc, a1 = 0.f, a2 = 0.f, a3 = 0.f;
    #pragma unroll
    for (int kq=0; kq<8; ++kq){
      uint4 hq0 = hv[kq*2], hq1 = hv[kq*2+1];
      a0 = FDOT2(as_h2(hq0.x), w[kq*8+0], a0); a1 = FDOT2(as_h2(hq0.y), w[kq*8+1], a1);
      a2 = FDOT2(as_h2(hq0.z), w[kq*8+2], a2); a3 = FDOT2(as_h2(hq0.w), w[kq*8+3], a3);
      a0 = FDOT2(as_h2(hq1.x), w[kq*8+4], a0); a1 = FDOT2(as_h2(hq1.y), w[kq*8+5], a1);
      a2 = FDOT2(as_h2(hq1.z), w[kq*8+6], a2); a3 = FDOT2(as_h2(hq1.w), w[kq*8+7], a3);
    }
    float a = (a0 + a1) + (a2 + a3);
    // own activation: sigmoid for g in {0,1,3}, tanh via scaled sigmoid for g==2
    float s  = 1.f/(1.f + __expf(-km*a));
    float act = (g == 2) ? (2.f*s - 1.f) : s;
    // intra-quad all-to-all via DPP quad_perm (pure VALU)
    float u1 = qperm<QP_XOR1>(act);
    float u2 = qperm<QP_XOR2>(act);
    float u3 = qperm<QP_XOR3>(act);
    // gate_j = u[g^j]; select with 8 cndmasks
    float pl = b0 ? u1  : act;   // u[b0]
    float ph = b0 ? u3  : u2;    // u[2|b0]
    float ql = b0 ? act : u1;    // u[!b0]
    float qh = b0 ? u2  : u3;    // u[2|!b0]
    float i_ = b1 ? ph : pl;     // gate 0
    float f_ = b1 ? qh : ql;     // gate 1
    float g_ = b1 ? pl : ph;     // gate 2
    float o_ = b1 ? ql : qh;     // gate 3
    creg = f_*creg + i_*g_;
    float ec = __expf(2.f*creg); float tc = 1.f - 2.f/(ec+1.f);
    hreg = o_*tc;
    if (g == 0){
      union{ _Float16 f; unsigned short s; } cv; cv.f = (_Float16)hreg;
      hsh[(t+1) & 1][d] = cv.s;
    }
    __syncthreads();
    xc = xa; xa = xb;
  }

  // fused FC: out[b] = sum_d h_d * fcw[d] + fcb
  if (g == 0) red[d] = hreg * fcw[d];
  __syncthreads();
  #pragma unroll
  for (int s2=64; s2>=1; s2>>=1){
    if (tid < s2) red[tid] += red[tid+s2];
    __syncthreads();
  }
  if (tid == 0) out[b] = red[0] + fcb[0];
}

extern "C" void kernel_launch(void* const* d_in, const int* in_sizes, int n_in,
                              void* d_out, int out_size, void* d_ws, size_t ws_size,
                              hipStream_t stream){
  const float* x   = (const float*)d_in[0];
  const float* Wih = (const float*)d_in[1];
  const float* Whh = (const float*)d_in[2];
  const float* bih = (const float*)d_in[3];
  const float* bhh = (const float*)d_in[4];
  const float* fcw = (const float*)d_in[5];
  const float* fcb = (const float*)d_in[6];
  float* out = (float*)d_out;
  char* ws = (char*)d_ws;

  // ws layout (bytes):
  //   (x16 region 0..83,886,080 now unused — conv_x eliminated)
  //   W16  : 83,886,080 .. +327,680     (512*320 f16, rows permuted d*4+g)
  //   Whh2 : 84,213,760 .. +131,072     (512*64 half2, rows permuted d*4+g)
  //   bias : 84,344,832 .. +2,048       (512 f32, permuted d*4+g)
  //   xg   : 84,346,880 .. +268,435,456 (131072*512 f32, cols permuted d*4+g)
  unsigned int* W16   = (unsigned int*)(ws + 83886080);
  unsigned int* Whh2w = (unsigned int*)(ws + 84213760);
  float*        bias  = (float*)      (ws + 84344832);
  float*        xg    = (float*)      (ws + 84346880);

  hipLaunchKernelGGL(conv_small, dim3(450),    dim3(256), 0, stream, Wih, Whh, bih, bhh, W16, Whh2w, bias);
  hipLaunchKernelGGL(gemm16,     dim3(1024,4), dim3(256), 0, stream,
                     x, (const _Float16*)W16, bias, xg);
  hipLaunchKernelGGL(lstm_rec,   dim3(256),    dim3(512), 0, stream, xg, Whh2w, fcw, fcb, out);
}

// Round 8
// 631.065 us; speedup vs baseline: 1.4022x; 1.4022x over previous
//
#include <hip/hip_runtime.h>
#include <cstdint>
#include <cstddef>

// Problem constants
#define Bb   256
#define Tt   512
#define Ii   300
#define Hh   128
#define G4   512      // 4*H
#define KP   320      // K padded to multiple of 32 for MFMA
#define Mm   (Bb*Tt)  // 131072 rows of phase-1 GEMM

typedef _Float16 h2v   __attribute__((ext_vector_type(2)));
typedef _Float16 half8 __attribute__((ext_vector_type(8)));
typedef float    f32x4 __attribute__((ext_vector_type(4)));

static __device__ __forceinline__ h2v as_h2(unsigned int u){ union{unsigned int u; h2v h;} c; c.u=u; return c.h; }
static __device__ __forceinline__ unsigned int as_u32(h2v h){ union{unsigned int u; h2v h;} c; c.h=h; return c.u; }

#if __has_builtin(__builtin_amdgcn_fdot2)
#define FDOT2(a,b,c) __builtin_amdgcn_fdot2((a),(b),(c),false)
#else
static __device__ __forceinline__ float FDOT2(h2v a, h2v b, float c){
  return c + (float)a[0]*(float)b[0] + (float)a[1]*(float)b[1];
}
#endif

// async global->LDS, 16 B per lane. LDS dest is WAVE-UNIFORM base + lane*16;
// global src is per-lane. Fallback preserves identical semantics.
#if __has_builtin(__builtin_amdgcn_global_load_lds)
static __device__ __forceinline__ void gload_lds16(const _Float16* g, _Float16* l){
  __builtin_amdgcn_global_load_lds((const __attribute__((address_space(1))) void*)g,
                                   (__attribute__((address_space(3))) void*)l, 16, 0, 0);
}
#else
static __device__ __forceinline__ void gload_lds16(const _Float16* g, _Float16* l){
  int lane = threadIdx.x & 63;
  *(uint4*)((char*)l + lane*16) = *(const uint4*)g;
}
#endif

// ---------------- conversion: x fp32 [131072,300] -> f16 padded [131072,320] ----------------
__global__ __launch_bounds__(256) void conv_x(const float* __restrict__ x, unsigned int* __restrict__ x16){
  int idx = blockIdx.x*256 + threadIdx.x;      // half2 index; total 131072*160, grid exact
  int r   = idx / 160;
  int kk2 = idx - r*160;
  int kk  = kk2*2;
  const float* xr = x + (size_t)r*Ii;
  float v0 = (kk   < Ii) ? xr[kk]   : 0.f;
  float v1 = (kk+1 < Ii) ? xr[kk+1] : 0.f;
  h2v h; h[0] = (_Float16)v0; h[1] = (_Float16)v1;
  x16[idx] = as_u32(h);
}

// ---------------- conversion: W_ih -> f16 padded (rows PERMUTED pr=d*4+g), Whh packed, bias sum ---
// Row permutation: output row pr corresponds to original gate row gc = (pr&3)*128 + (pr>>2).
__global__ __launch_bounds__(256) void conv_small(const float* __restrict__ Wih, const float* __restrict__ Whh,
      const float* __restrict__ bih, const float* __restrict__ bhh,
      unsigned int* __restrict__ W16, unsigned int* __restrict__ Whh2, float* __restrict__ bias){
  int idx = blockIdx.x*256 + threadIdx.x;
  if (idx < G4*160){
    int pr = idx/160, kk2 = idx - pr*160, kk = kk2*2;
    int gc = (pr&3)*128 + (pr>>2);
    const float* wr = Wih + (size_t)gc*Ii;
    float v0 = (kk   < Ii) ? wr[kk]   : 0.f;
    float v1 = (kk+1 < Ii) ? wr[kk+1] : 0.f;
    h2v h; h[0]=(_Float16)v0; h[1]=(_Float16)v1;
    W16[idx] = as_u32(h);
  } else if (idx < G4*160 + G4*64){
    int t = idx - G4*160; int pr = t>>6, kk = t&63;
    int gc = (pr&3)*128 + (pr>>2);
    float v0 = Whh[gc*Hh + kk*2], v1 = Whh[gc*Hh + kk*2 + 1];
    h2v h; h[0]=(_Float16)v0; h[1]=(_Float16)v1;
    Whh2[t] = as_u32(h);
  } else if (idx < G4*160 + G4*64 + G4){
    int pr = idx - (G4*160 + G4*64);
    int gc = (pr&3)*128 + (pr>>2);
    bias[pr] = bih[gc] + bhh[gc];
  }
}

// ---------------- phase 1: xg[131072,512] = A16 @ W16^T + bias, f16 MFMA ----------------
// Staging via global_load_lds width-16 (m97 pattern: the proven +67% lever for this
// exact 2-barrier structure). Wave w stages rows [w*32, w*32+32) of each 128x32 tile
// with 2 instrs per matrix: lds dest = &tile[w*32 + r*16][0] (wave-uniform), lane i's
// 16 B lands at row w*32+r*16+(i>>2), halves (i&3)*8..+8 — matching its global addr.
__global__ __launch_bounds__(256) void gemm16(const _Float16* __restrict__ A, const _Float16* __restrict__ Bm,
       const float* __restrict__ bias, float* __restrict__ C){
  __shared__ _Float16 As[128][32];
  __shared__ _Float16 Bs[128][32];
  int tid = threadIdx.x;
  int w = tid>>6, lane = tid&63;
  int bm = blockIdx.x*128, bn = blockIdx.y*128;
  f32x4 acc[2][8];
  #pragma unroll
  for (int i=0;i<2;i++)
    #pragma unroll
    for (int j=0;j<8;j++) acc[i][j] = (f32x4){0.f,0.f,0.f,0.f};

  int rr = lane>>2;             // 0..15: row within 16-row chunk
  int ch = (lane&3)*8;          // half-index within 32-half row chunk
  const _Float16* gA0 = A  + (size_t)(bm + w*32      + rr)*KP + ch;
  const _Float16* gA1 = A  + (size_t)(bm + w*32 + 16 + rr)*KP + ch;
  const _Float16* gB0 = Bm + (size_t)(bn + w*32      + rr)*KP + ch;
  const _Float16* gB1 = Bm + (size_t)(bn + w*32 + 16 + rr)*KP + ch;
  _Float16* lA0 = &As[w*32][0];
  _Float16* lA1 = &As[w*32+16][0];
  _Float16* lB0 = &Bs[w*32][0];
  _Float16* lB1 = &Bs[w*32+16][0];

  int q = lane>>4, mr = lane&15;
  int m0 = w*32;

  for (int kt=0; kt<KP/32; ++kt){
    __syncthreads();                      // previous tile fully consumed (WAR)
    gload_lds16(gA0, lA0);
    gload_lds16(gA1, lA1);
    gload_lds16(gB0, lB0);
    gload_lds16(gB1, lB1);
    gA0 += 32; gA1 += 32; gB0 += 32; gB1 += 32;   // advance 32 halves
    __syncthreads();                      // vmcnt(0) drain -> tile resident
    half8 af0 = *(const half8*)&As[m0 + mr][q*8];
    half8 af1 = *(const half8*)&As[m0 + 16 + mr][q*8];
    #pragma unroll
    for (int j=0;j<8;j++){
      half8 bf = *(const half8*)&Bs[j*16 + mr][q*8];
      acc[0][j] = __builtin_amdgcn_mfma_f32_16x16x32_f16(af0, bf, acc[0][j], 0,0,0);
      acc[1][j] = __builtin_amdgcn_mfma_f32_16x16x32_f16(af1, bf, acc[1][j], 0,0,0);
    }
  }
  // epilogue: C/D layout col=lane&15, row=(lane>>4)*4+reg
  #pragma unroll
  for (int j=0;j<8;j++){
    int gc = bn + j*16 + mr;
    float bv = bias[gc];
    #pragma unroll
    for (int i=0;i<2;i++){
      int gr0 = bm + w*32 + i*16 + q*4;
      #pragma unroll
      for (int reg=0; reg<4; ++reg)
        C[(size_t)(gr0+reg)*G4 + gc] = acc[i][j][reg] + bv;
    }
  }
}

// ---------------- phase 2: recurrence, one block per batch row (R1 VERBATIM — measured 343 us) ---
// 512 threads; thread t owns gate row tid=d*4+g. Gate exchange via __shfl_xor within
// the 4-lane group; one barrier per step via double-buffered hsh; 1-step xg prefetch.
__global__ __launch_bounds__(512,1) void lstm_rec(const float* __restrict__ xg, const unsigned int* __restrict__ Whh2,
     const float* __restrict__ fcw, const float* __restrict__ fcb, float* __restrict__ out){
  int tid = threadIdx.x;           // 0..511
  int b = blockIdx.x;
  int d = tid >> 2, g = tid & 3;
  h2v w[64];
  #pragma unroll
  for (int kk=0; kk<64; ++kk) w[kk] = as_h2(Whh2[tid*64 + kk]);

  __shared__ __align__(16) unsigned short hsh[2][128];
  __shared__ float red[128];
  if (tid < 128) hsh[0][tid] = 0;
  float creg = 0.f, hreg = 0.f;
  const float* xrow = xg + (size_t)b * (Tt*G4);
  float xc = xrow[tid];
  int b0 = g & 1;
  int b1 = (g >> 1) & 1;
  float km = (g == 2) ? 2.f : 1.f;   // tanh(a) = 2*sigmoid(2a)-1
  __syncthreads();

  for (int t=0; t<Tt; ++t){
    float xn = 0.f;
    if (t < Tt-1) xn = xrow[(size_t)(t+1)*G4 + tid];
    const uint4* hv = (const uint4*)hsh[t & 1];
    float a0 = xc, a1 = 0.f, a2 = 0.f, a3 = 0.f;
    #pragma unroll
    for (int kq=0; kq<8; ++kq){
      uint4 hq0 = hv[kq*2], hq1 = hv[kq*2+1];
      a0 = FDOT2(as_h2(hq0.x), w[kq*8+0], a0); a1 = FDOT2(as_h2(hq0.y), w[kq*8+1], a1);
      a2 = FDOT2(as_h2(hq0.z), w[kq*8+2], a2); a3 = FDOT2(as_h2(hq0.w), w[kq*8+3], a3);
      a0 = FDOT2(as_h2(hq1.x), w[kq*8+4], a0); a1 = FDOT2(as_h2(hq1.y), w[kq*8+5], a1);
      a2 = FDOT2(as_h2(hq1.z), w[kq*8+6], a2); a3 = FDOT2(as_h2(hq1.w), w[kq*8+7], a3);
    }
    float a = (a0 + a1) + (a2 + a3);
    // own activation: sigmoid for g in {0,1,3}, tanh via scaled sigmoid for g==2
    float s  = 1.f/(1.f + __expf(-km*a));
    float act = (g == 2) ? (2.f*s - 1.f) : s;
    // intra-wave all-to-all within the 4-lane group: u[k] = act of gate (g^k)
    float u1 = __shfl_xor(act, 1);
    float u2 = __shfl_xor(act, 2);
    float u3 = __shfl_xor(act, 3);
    // act_j = u[g^j]; select with 8 cndmasks
    float pl = b0 ? u1  : act;   // u[b0]
    float ph = b0 ? u3  : u2;    // u[2|b0]
    float ql = b0 ? act : u1;    // u[!b0]
    float qh = b0 ? u2  : u3;    // u[2|!b0]
    float i_ = b1 ? ph : pl;     // gate 0
    float f_ = b1 ? qh : ql;     // gate 1
    float g_ = b1 ? pl : ph;     // gate 2
    float o_ = b1 ? ql : qh;     // gate 3
    creg = f_*creg + i_*g_;
    float ec = __expf(2.f*creg); float tc = 1.f - 2.f/(ec+1.f);
    hreg = o_*tc;
    if (g == 0){
      union{ _Float16 f; unsigned short s; } cv; cv.f = (_Float16)hreg;
      hsh[(t+1) & 1][d] = cv.s;
    }
    __syncthreads();
    xc = xn;
  }

  // fused FC: out[b] = sum_d h_d * fcw[d] + fcb
  if (g == 0) red[d] = hreg * fcw[d];
  __syncthreads();
  #pragma unroll
  for (int s2=64; s2>=1; s2>>=1){
    if (tid < s2) red[tid] += red[tid+s2];
    __syncthreads();
  }
  if (tid == 0) out[b] = red[0] + fcb[0];
}

extern "C" void kernel_launch(void* const* d_in, const int* in_sizes, int n_in,
                              void* d_out, int out_size, void* d_ws, size_t ws_size,
                              hipStream_t stream){
  const float* x   = (const float*)d_in[0];
  const float* Wih = (const float*)d_in[1];
  const float* Whh = (const float*)d_in[2];
  const float* bih = (const float*)d_in[3];
  const float* bhh = (const float*)d_in[4];
  const float* fcw = (const float*)d_in[5];
  const float* fcb = (const float*)d_in[6];
  float* out = (float*)d_out;
  char* ws = (char*)d_ws;

  // ws layout (bytes):
  //   x16  : 0          .. 83,886,080   (131072*320 f16)
  //   W16  : 83,886,080 .. +327,680     (512*320 f16, rows permuted d*4+g)
  //   Whh2 : 84,213,760 .. +131,072     (512*64 half2, rows permuted d*4+g)
  //   bias : 84,344,832 .. +2,048       (512 f32, permuted d*4+g)
  //   xg   : 84,346,880 .. +268,435,456 (131072*512 f32, cols permuted d*4+g)
  unsigned int* x16   = (unsigned int*)(ws);
  unsigned int* W16   = (unsigned int*)(ws + 83886080);
  unsigned int* Whh2w = (unsigned int*)(ws + 84213760);
  float*        bias  = (float*)      (ws + 84344832);
  float*        xg    = (float*)      (ws + 84346880);

  hipLaunchKernelGGL(conv_x,     dim3(81920),  dim3(256), 0, stream, x, x16);
  hipLaunchKernelGGL(conv_small, dim3(450),    dim3(256), 0, stream, Wih, Whh, bih, bhh, W16, Whh2w, bias);
  hipLaunchKernelGGL(gemm16,     dim3(1024,4), dim3(256), 0, stream,
                     (const _Float16*)x16, (const _Float16*)W16, bias, xg);
  hipLaunchKernelGGL(lstm_rec,   dim3(256),    dim3(512), 0, stream, xg, Whh2w, fcw, fcb, out);
}